// Round 7
// baseline (558.167 us; speedup 1.0000x reference)
//
#include <hip/hip_runtime.h>
#include <hip/hip_bf16.h>
#include <cstdint>
#include <cstddef>

typedef unsigned short u16;
typedef unsigned int   u32;

typedef __bf16 bf16x8 __attribute__((ext_vector_type(8)));
typedef float  f32x4  __attribute__((ext_vector_type(4)));
typedef float  f32x16 __attribute__((ext_vector_type(16)));
typedef u16    u16x4  __attribute__((ext_vector_type(4)));
typedef u16    u16x8  __attribute__((ext_vector_type(8)));
typedef u32    u32x4  __attribute__((ext_vector_type(4)));

#define DEV static __device__ __forceinline__
#define VMCNT(n) asm volatile("s_waitcnt vmcnt(" #n ")" ::: "memory")
#define LGKM0    asm volatile("s_waitcnt lgkmcnt(0)" ::: "memory")
#define SBARF    do { asm volatile("" ::: "memory"); __builtin_amdgcn_s_barrier(); asm volatile("" ::: "memory"); } while (0)

DEV u16 f2bf(float f){
  union { float f; u32 u; } v; v.f = f;
  u32 r = v.u + 0x7fffu + ((v.u >> 16) & 1u);
  return (u16)(r >> 16);
}
DEV float bf2f(u16 h){
  union { u32 u; float f; } v; v.u = ((u32)h) << 16;
  return v.f;
}
DEV u32 pk2(float a, float b){
  __hip_bfloat16 x = __float2bfloat16(a), y = __float2bfloat16(b);
  return (u32)__builtin_bit_cast(u16, x) | ((u32)__builtin_bit_cast(u16, y) << 16);
}
DEV float fexp2(float x){ float r; asm("v_exp_f32 %0, %1" : "=v"(r) : "v"(x)); return r; }
DEV float mx3(float a, float b, float c){ return fmaxf(fmaxf(a, b), c); }
DEV float tree16(const f32x16& p){
  float a = mx3(p[0],p[1],p[2]),  b = mx3(p[3],p[4],p[5]);
  float c = mx3(p[6],p[7],p[8]),  d = mx3(p[9],p[10],p[11]);
  float e = mx3(p[12],p[13],p[14]);
  return fmaxf(mx3(a,b,c), mx3(d,e,p[15]));
}
DEV void gll16(const void* g, void* l){
  __builtin_amdgcn_global_load_lds(
      (const __attribute__((address_space(1))) u32*)g,
      (__attribute__((address_space(3))) u32*)l, 16, 0, 0);
}

// ---------------- fused converts + RoPE table ----------------
// w1 layout: rows 0..1536 = q_a_w; 1536..2048 = kv_a_w (c_kv part);
// 2048..2112 = kv_a_w k_pe rows ROPE-PERMUTED (even dims at j<32, odd at
// j>=32, matching the q_pe weight permutation) -- consumed by the kpe path.
__global__ void k_cvt_all(const float* __restrict__ x,  const float* __restrict__ qaw,
                          const float* __restrict__ kvaw, const float* __restrict__ qbw,
                          const float* __restrict__ kvbw, const float* __restrict__ ow,
                          u16* __restrict__ xb, u16* __restrict__ w1, u16* __restrict__ wqb,
                          u16* __restrict__ wkvb, u16* __restrict__ wo,
                          float* __restrict__ tab){
  const long stride = (long)gridDim.x * blockDim.x;
  for (long i = (long)blockIdx.x * blockDim.x + threadIdx.x; i < 8192000L; i += stride){
    if (i >= 8126464L){
      int idx = (int)(i - 8126464L);          // 65536 entries
      int s = idx >> 5, p = idx & 31;
      float freq = exp2f(-(float)p * 0.41524101186f);   // log2(10000)/32
      float ang = (float)s * freq;
      tab[idx*2]   = cosf(ang);
      tab[idx*2+1] = sinf(ang);
      continue;
    }
    const float* src; u16* dst;
    if (i < 4194304L){ long e = i*4; src = x + e; dst = xb + e; }
    else if (i < 5373952L){
      long e = (i - 4194304L) * 4;
      int row = (int)(e >> 11), col = (int)(e & 2047);
      dst = w1 + e;
      if (row < 1536) src = qaw + (long)row*2048 + col;
      else if (row < 2048) src = kvaw + (long)(row-1536)*2048 + col;
      else if (row < 2112){
        int j = row - 2048;
        int sj = (j < 32) ? (2*j) : (2*(j-32)+1);      // rope-permute k_pe rows
        src = kvaw + (long)(512 + sj)*2048 + col;
      }
      else { u16x4 z; z[0]=0;z[1]=0;z[2]=0;z[3]=0; *(u16x4*)dst = z; continue; }
    }
    else if (i < 6553600L){
      long e = (i - 5373952L)*4;
      int row = (int)(e / 1536), col = (int)(e - (long)row*1536);
      int dd = row % 192;
      int srow = row;
      if (dd >= 128){
        int j = dd - 128;
        int sdd = (j < 32) ? (128 + 2*j) : (128 + 2*(j - 32) + 1);
        srow = row - dd + sdd;
      }
      src = qbw + (long)srow*1536 + col; dst = wqb + e;
    }
    else if (i < 7077888L){ long e = (i - 6553600L)*4; src = kvbw + e; dst = wkvb + e; }
    else { long e = (i - 7077888L)*4; src = ow + e; dst = wo + e; }
    f32x4 f = *(const f32x4*)src;
    u16x4 o4;
    o4[0]=f2bf(f[0]); o4[1]=f2bf(f[1]); o4[2]=f2bf(f[2]); o4[3]=f2bf(f[3]);
    *(u16x4*)dst = o4;
  }
}

// ---------------- 256x256 8-wave 4-phase GEMM body ----------------
// CMODE: 0 = bf16 store (masked at Nlim), 1 = f32 store,
//        2 = kv-split (k_nope rowmajor + V fragment-major VTf layout:
//            [bh][kt][dblk][slot][lane][8], slot = sigma(kk)>>3, so the attn
//            PV A-fragment is one coalesced 16B/lane wave load),
//        3 = bf16 store with fused q_pe RoPE (table-based, rope-permuted weights)
template<int CMODE>
DEV void gemm_body(u16 (*sm)[32768], int bm, int bn,
                   const u16* __restrict__ A, int lda,
                   const u16* __restrict__ B, int ldb,
                   void* __restrict__ Cp, int ldc, int K, int Nlim,
                   u16* __restrict__ kn, u16* __restrict__ vt,
                   const float* __restrict__ tab)
{
  const int tid = threadIdx.x;
  const int l   = tid & 63;
  const int wv  = tid >> 6;
  const int wr  = wv >> 2, wc = wv & 3;
  const int l15 = l & 15, l4 = l >> 4;
  const long M0 = (long)bm * 256, N0 = (long)bn * 256;

  const int c7 = tid & 7;
  const u16* asrc[4]; const u16* bsrc[4];
  int dsta[4], dstb[4];
  #pragma unroll
  for (int s = 0; s < 4; ++s){
    int slot = s*512 + tid;
    int row  = slot >> 3;
    asrc[s] = A + (M0 + row)*lda + ((c7 ^ (row & 7)) << 3);
    bsrc[s] = B + (N0 + row)*ldb + ((c7 ^ (row & 7)) << 3);
    dsta[s] = slot*8;
    dstb[s] = 16384 + slot*8;
  }
  auto stA = [&](int s, int kt, int nb){ gll16(asrc[s] + (long)kt*64, &sm[nb][dsta[s]]); };
  auto stB = [&](int s, int kt, int nb){ gll16(bsrc[s] + (long)kt*64, &sm[nb][dstb[s]]); };

  auto rdA = [&](int buf, int m, int ks) -> bf16x8 {
    int row = wr*128 + m*16 + l15;
    int ch  = ks*4 + l4;
    return *(const bf16x8*)&sm[buf][row*64 + ((ch ^ (row & 7)) << 3)];
  };
  auto rdB = [&](int buf, int n, int ks) -> bf16x8 {
    int row = wc*64 + n*16 + l15;
    int ch  = ks*4 + l4;
    return *(const bf16x8*)&sm[buf][16384 + row*64 + ((ch ^ (row & 7)) << 3)];
  };

  f32x4 acc[8][4];
  #pragma unroll
  for (int m = 0; m < 8; ++m)
    #pragma unroll
    for (int n = 0; n < 4; ++n)
      acc[m][n] = (f32x4)0.0f;

  stB(0,0,0); stB(2,0,0); stB(1,0,0); stB(3,0,0);
  stA(0,0,0); stA(2,0,0); stA(1,0,0); stA(3,0,0);
  VMCNT(2);
  SBARF;

  const int NT = K >> 6;
  for (int t = 0; t < NT; ++t){
    const int cb = t & 1, nb = cb ^ 1;
    const bool PF = (t + 1 < NT);
    bf16x8 bfr[4][2];
    #pragma unroll
    for (int p = 0; p < 4; ++p){
      bf16x8 af[2][2];
      #pragma unroll
      for (int mm = 0; mm < 2; ++mm)
        #pragma unroll
        for (int ks = 0; ks < 2; ++ks)
          af[mm][ks] = rdA(cb, p*2 + mm, ks);
      if (p == 0){
        #pragma unroll
        for (int n = 0; n < 4; ++n)
          #pragma unroll
          for (int ks = 0; ks < 2; ++ks)
            bfr[n][ks] = rdB(cb, n, ks);
        if (PF){ stB(0, t+1, nb); stB(2, t+1, nb); }
      } else if (p == 1){
        if (PF){ stB(1, t+1, nb); stB(3, t+1, nb); }
      } else if (p == 2){
        if (PF){ stA(0, t+1, nb); stA(2, t+1, nb); }
      } else {
        if (PF){ stA(1, t+1, nb); stA(3, t+1, nb); }
      }
      SBARF;
      LGKM0;
      __builtin_amdgcn_s_setprio(1);
      #pragma unroll
      for (int mm = 0; mm < 2; ++mm)
        #pragma unroll
        for (int n = 0; n < 4; ++n)
          #pragma unroll
          for (int ks = 0; ks < 2; ++ks)
            acc[p*2+mm][n] = __builtin_amdgcn_mfma_f32_16x16x32_bf16(af[mm][ks], bfr[n][ks], acc[p*2+mm][n], 0, 0, 0);
      __builtin_amdgcn_s_setprio(0);
      if (p == 1){ if (PF) VMCNT(4); else VMCNT(0); }
      if (p == 3 && PF) VMCNT(2);
      SBARF;
    }
  }

  const long rbase = M0 + wr*128 + l4*4;
  const long cbase = N0 + wc*64 + l15;

  if (CMODE == 3){
    const bool ropeblk = (((N0 + wc*64) % 192) == 128);
    if (ropeblk){
      #pragma unroll
      for (int n = 0; n < 2; ++n){
        const int p = l15 + 16*n;
        #pragma unroll
        for (int m = 0; m < 8; ++m){
          #pragma unroll
          for (int i = 0; i < 4; ++i){
            long r = rbase + m*16 + i;
            const float* cs2 = tab + (((int)(r & 2047))*32 + p)*2;
            float cs = cs2[0], sn = cs2[1];
            float e = acc[m][n][i], o = acc[m][n+2][i];
            ((u16*)Cp)[r * ldc + cbase + n*16]       = f2bf(e*cs - o*sn);
            ((u16*)Cp)[r * ldc + cbase + (n+2)*16]   = f2bf(o*cs + e*sn);
          }
        }
      }
    } else {
      #pragma unroll
      for (int m = 0; m < 8; ++m)
        #pragma unroll
        for (int n = 0; n < 4; ++n)
          #pragma unroll
          for (int i = 0; i < 4; ++i)
            ((u16*)Cp)[(rbase + m*16 + i) * ldc + cbase + n*16] = f2bf(acc[m][n][i]);
    }
    return;
  }

  #pragma unroll
  for (int m = 0; m < 8; ++m){
    #pragma unroll
    for (int n = 0; n < 4; ++n){
      const long c  = cbase + n*16;
      const long r0 = rbase + m*16;
      if (CMODE == 0){
        if (c < Nlim){
          #pragma unroll
          for (int i = 0; i < 4; ++i)
            ((u16*)Cp)[(r0 + i) * ldc + c] = f2bf(acc[m][n][i]);
        }
      } else if (CMODE == 1){
        #pragma unroll
        for (int i = 0; i < 4; ++i)
          ((float*)Cp)[(r0 + i) * ldc + c] = acc[m][n][i];
      } else {
        int h = (int)(c >> 8), rem = (int)(c & 255);
        if (rem < 128){
          #pragma unroll
          for (int i = 0; i < 4; ++i)
            kn[(r0 + i) * 2048 + h*128 + rem] = f2bf(acc[m][n][i]);
        } else {
          // V fragment-major: VTf[bh][kt][dblk][slot][lane][8]
          //   token s -> kt = s>>6, kk = s&63, kkp = sigma(kk) (swap 4-blocks
          //   1<->2 within 16); slot = kkp>>3, e = kkp&7.
          // r0%4==0 and sigma preserves 4-runs -> u16x4 store stays contiguous.
          int bb = (int)(r0 >> 11), s = (int)(r0 & 2047);
          int kk = s & 63;
          int kkp = (kk & ~12) | ((kk & 4) << 1) | ((kk & 8) >> 1);
          int kt = s >> 6;
          int dfull = rem - 128;
          int bh = bb*16 + h;
          long idx = ((((long)bh*32 + kt)*4 + (dfull>>5))*8 + (kkp>>3))*256
                   + (dfull & 31)*8 + (kkp & 7);
          u16x4 pv;
          #pragma unroll
          for (int i = 0; i < 4; ++i) pv[i] = f2bf(acc[m][n][i]);
          *(u16x4*)&vt[idx] = pv;
        }
      }
    }
  }
}

template<int CMODE>
__global__ __launch_bounds__(512, 1)
void k_gemm8(const u16* __restrict__ A, int lda,
             const u16* __restrict__ B, int ldb,
             void* __restrict__ Cp, int ldc, int K, int Nlim, int gy,
             u16* __restrict__ kn, u16* __restrict__ vt)
{
  __shared__ u16 sm[2][32768];
  const int flat = blockIdx.x;
  const int id2  = (flat & 7) * ((int)gridDim.x >> 3) + (flat >> 3);
  gemm_body<CMODE>(sm, id2 / gy, id2 % gy, A, lda, B, ldb, Cp, ldc, K, Nlim, kn, vt, nullptr);
}

// fused q_b (+RoPE via table) + kv_b: grid 896; per XCD: 48 q_b + 64 kv_b blocks
__global__ __launch_bounds__(512, 1)
void k_gemm_qbkvb(const u16* __restrict__ qackv, const u16* __restrict__ wqb,
                  const u16* __restrict__ wkvb, u16* __restrict__ q,
                  u16* __restrict__ kn, u16* __restrict__ vt,
                  const float* __restrict__ tab)
{
  __shared__ u16 sm[2][32768];
  const int flat = blockIdx.x;
  const int grp = flat >> 3, sub = flat & 7;
  if (grp < 48){
    int i = sub*48 + grp;
    gemm_body<3>(sm, i/12, i%12, qackv, 2176, wqb, 1536, q, 3072, 1536, 3072, nullptr, nullptr, tab);
  } else {
    int i = sub*64 + (grp - 48);
    gemm_body<2>(sm, i/16, i%16, qackv + 1536, 2176, wkvb, 512, nullptr, 0, 512, 4096, kn, vt, nullptr);
  }
}

// ---------------- RMS norms (vectorized) + k_pe GEMM tail blocks ----------------
// Blocks 0..8191: per-token RMS norm (q part: u16x8 chunks, 192 active
// threads; kv part: one u32 per thread). Blocks 8192..8319: k_pe GEMM
// (M=8192, N=64, K=2048) + fused RoPE -- 4 waves/block, 16 rows/wave,
// register-only MFMA, B panel (64 rows of w1, 256KB) L2-resident. Same
// 512-wave kpe parallelism as the former k_kpe dispatch, but merged here
// (low-register kernel: no regalloc risk to the GEMM bodies -- round-6
// lesson) to save one launch boundary.
__global__ __launch_bounds__(256)
void k_normrope(u16* __restrict__ qackv, const float* __restrict__ qln,
                const float* __restrict__ kvln,
                const u16* __restrict__ xb, const u16* __restrict__ w1,
                const float* __restrict__ tab){
  const int tid = threadIdx.x;
  if (blockIdx.x >= 8192){
    const int l   = tid & 63;
    const int l15 = l & 15, l4 = l >> 4;
    const int wvk = tid >> 6;
    const long M0 = ((long)(blockIdx.x - 8192)*4 + wvk) * 16;

    f32x4 acc[4];
    #pragma unroll
    for (int n = 0; n < 4; ++n) acc[n] = (f32x4)0.0f;

    const u16* aptr = xb + (M0 + l15)*2048 + l4*8;
    const u16* bptr = w1 + (2048 + l15)*2048 + l4*8;

    #pragma unroll 2
    for (int kt = 0; kt < 32; ++kt){
      bf16x8 a[2], b[4][2];
      #pragma unroll
      for (int ks = 0; ks < 2; ++ks)
        a[ks] = *(const bf16x8*)(aptr + kt*64 + ks*32);
      #pragma unroll
      for (int n = 0; n < 4; ++n)
        #pragma unroll
        for (int ks = 0; ks < 2; ++ks)
          b[n][ks] = *(const bf16x8*)(bptr + (long)n*16*2048 + kt*64 + ks*32);
      #pragma unroll
      for (int n = 0; n < 4; ++n)
        #pragma unroll
        for (int ks = 0; ks < 2; ++ks)
          acc[n] = __builtin_amdgcn_mfma_f32_16x16x32_bf16(a[ks], b[n][ks], acc[n], 0, 0, 0);
    }

    // cols: c = n*16 + l15 in rope-permuted space (even part c<32, odd c>=32)
    #pragma unroll
    for (int n = 0; n < 2; ++n){
      const int p = l15 + 16*n;
      #pragma unroll
      for (int i = 0; i < 4; ++i){
        long r = M0 + l4*4 + i;
        const float* cs2 = tab + (((int)(r & 2047))*32 + p)*2;
        float cs = cs2[0], sn = cs2[1];
        float e = acc[n][i], o = acc[n+2][i];
        qackv[r*2176 + 2048 + p]      = f2bf(e*cs - o*sn);
        qackv[r*2176 + 2048 + 32 + p] = f2bf(o*cs + e*sn);
      }
    }
    return;
  }

  const int tok = blockIdx.x;
  u16* row = qackv + (long)tok * 2176;
  __shared__ float red[8];

  float v[8]; float ss = 0.f;
  if (tid < 192){
    u16x8 h8 = *(const u16x8*)(row + tid*8);
    #pragma unroll
    for (int i = 0; i < 8; ++i){ v[i] = bf2f(h8[i]); ss += v[i]*v[i]; }
  }
  #pragma unroll
  for (int m = 32; m >= 1; m >>= 1) ss += __shfl_xor(ss, m);
  if ((tid & 63) == 0) red[tid >> 6] = ss;

  u32 pair = *(const u32*)(row + 1536 + 2*tid);
  float u0 = bf2f((u16)(pair & 0xffff));
  float u1 = bf2f((u16)(pair >> 16));
  float s2 = u0*u0 + u1*u1;
  #pragma unroll
  for (int m = 32; m >= 1; m >>= 1) s2 += __shfl_xor(s2, m);
  if ((tid & 63) == 0) red[4 + (tid >> 6)] = s2;
  __syncthreads();

  float tot = red[0] + red[1] + red[2] + red[3];
  float r1 = rsqrtf(tot * (1.0f/1536.0f) + 1e-6f);
  if (tid < 192){
    u16x8 o8;
    #pragma unroll
    for (int i = 0; i < 8; ++i) o8[i] = f2bf(v[i] * r1 * qln[tid*8 + i]);
    *(u16x8*)(row + tid*8) = o8;
  }

  float tot2 = red[4] + red[5] + red[6] + red[7];
  float r2 = rsqrtf(tot2 * (1.0f/512.0f) + 1e-6f);
  u16 w0 = f2bf(u0 * r2 * kvln[2*tid]);
  u16 w1v = f2bf(u1 * r2 * kvln[2*tid + 1]);
  *(u32*)(row + 1536 + 2*tid) = (u32)w0 | ((u32)w1v << 16);
}

// ---------------- attention v13 (round-2 best): K in LDS (dbuf, 48KB);
// V fragment-major direct from global (coalesced 16B/lane, L1-resident:
// all 8 waves read the same 16KB tile). V loads pipelined: ks0/ks1 issued
// before softmax (latency hidden under VALU), ks2/ks3 between PV MFMA groups.
__global__ __launch_bounds__(512)
void k_attn11(const u16* __restrict__ Q, const u16* __restrict__ KN,
              const u16* __restrict__ CKV, const u16* __restrict__ VT,
              u16* __restrict__ O)
{
  __shared__ u16 sK[2][64*192];   // row stride 384B, XOR-swizzled content

  const int tid = threadIdx.x;
  const int l   = tid & 63;
  const int w   = tid >> 6;
  const int l31 = l & 31;
  const int hi  = l >> 5;
  const int swz = l31 & 7;
  const int flat = blockIdx.x;
  const int qb  = flat >> 6;
  const int bh  = ((flat & 7) << 3) | ((flat >> 3) & 7);
  const int b   = bh >> 4, h = bh & 15;
  const long tokbase = (long)b << 11;

  bf16x8 qf[12];
  {
    const u16* qptr = Q + (tokbase + qb*256 + w*32 + l31)*3072 + h*192 + hi*8;
    #pragma unroll
    for (int s = 0; s < 12; ++s)
      qf[s] = *(const bf16x8*)(qptr + s*16);
  }

  const u16* ksrc[3]; int kstep[3]; int kdst[3];
  #pragma unroll
  for (int i = 0; i < 3; ++i){
    int ch = tid + i*512;
    int row = ch / 24;
    int cc  = ch - row*24;
    int sc  = cc ^ (row & 7);
    if (sc < 16){ ksrc[i] = KN  + (tokbase + row)*2048 + h*128 + sc*8;       kstep[i] = 64*2048; }
    else        { ksrc[i] = CKV + (tokbase + row)*2176 + 2048 + (sc-16)*8;   kstep[i] = 64*2176; }
    kdst[i] = ch*8;
  }
  auto STAGE = [&](int kt, int nb){
    #pragma unroll
    for (int i = 0; i < 3; ++i) gll16(ksrc[i] + (long)kt*kstep[i], &sK[nb][kdst[i]]);
  };

  // V fragment base: VTf[bh][kt][dblk][slot][lane][8]; per-lane offset
  // hi*256 + l31*8 elems -> one wave load = contiguous 1KB.
  const u16* vbase = VT + (long)bh*(32*8192) + hi*256 + l31*8;

  f32x16 oacc[4];
  #pragma unroll
  for (int i = 0; i < 4; ++i) oacc[i] = (f32x16)0.0f;
  float mrun = -1e30f, lrun = 0.f;
  const float scale2 = (float)(0.07216878364870323 * 1.4426950408889634);  // 192^-0.5 * log2e

  STAGE(0, 0);
  __syncthreads();

  for (int kt = 0; kt < 32; ++kt){
    const int cur = kt & 1;
    if (kt < 31) STAGE(kt + 1, cur ^ 1);

    const char* kb = (const char*)&sK[cur][0];
    const u16*  vp = vbase + (long)kt*8192;

    f32x16 p0 = (f32x16)0.0f, p1 = (f32x16)0.0f;
    __builtin_amdgcn_s_setprio(1);
    #pragma unroll
    for (int s = 0; s < 12; ++s){
      const int co = ((2*s + hi) ^ swz) << 4;
      bf16x8 k0 = *(const bf16x8*)(kb + l31*384 + co);
      bf16x8 k1 = *(const bf16x8*)(kb + (32 + l31)*384 + co);
      p0 = __builtin_amdgcn_mfma_f32_32x32x16_bf16(k0, qf[s], p0, 0, 0, 0);
      p1 = __builtin_amdgcn_mfma_f32_32x32x16_bf16(k1, qf[s], p1, 0, 0, 0);
    }
    __builtin_amdgcn_s_setprio(0);

    // issue ks0/ks1 V fragments now -> latency hides under softmax VALU
    bf16x8 vA0 = *(const bf16x8*)(vp + 0);
    bf16x8 vA1 = *(const bf16x8*)(vp + 2048);
    bf16x8 vA2 = *(const bf16x8*)(vp + 4096);
    bf16x8 vA3 = *(const bf16x8*)(vp + 6144);
    bf16x8 vB0 = *(const bf16x8*)(vp + 512);
    bf16x8 vB1 = *(const bf16x8*)(vp + 2560);
    bf16x8 vB2 = *(const bf16x8*)(vp + 4608);
    bf16x8 vB3 = *(const bf16x8*)(vp + 6656);

    float rm = fmaxf(tree16(p0), tree16(p1));
    rm = fmaxf(rm, __shfl_xor(rm, 32));
    const float om = rm * scale2;
    if (!__all(om <= mrun + 8.0f)){          // defer-max (T13)
      float mn = fmaxf(mrun, om);
      float corr = fexp2(mrun - mn);
      mrun = mn;
      lrun *= corr;
      #pragma unroll
      for (int d = 0; d < 4; ++d)
        #pragma unroll
        for (int r = 0; r < 16; ++r) oacc[d][r] *= corr;
    }
    float ls = 0.f;
    #pragma unroll
    for (int r = 0; r < 16; ++r){ p0[r] = fexp2(__builtin_fmaf(p0[r], scale2, -mrun)); ls += p0[r]; }
    #pragma unroll
    for (int r = 0; r < 16; ++r){ p1[r] = fexp2(__builtin_fmaf(p1[r], scale2, -mrun)); ls += p1[r]; }
    lrun += ls + __shfl_xor(ls, 32);

    // PV: shuffle-free fragments (sigma k-permutation baked into VTf).
    bf16x8 pa[4];
    #pragma unroll
    for (int ks = 0; ks < 4; ++ks){
      const f32x16 ps = (ks < 2) ? p0 : p1;
      const int rb = (ks & 1) * 8;
      u32x4 aw;
      aw[0] = pk2(ps[rb+0], ps[rb+1]);
      aw[1] = pk2(ps[rb+2], ps[rb+3]);
      aw[2] = pk2(ps[rb+4], ps[rb+5]);
      aw[3] = pk2(ps[rb+6], ps[rb+7]);
      pa[ks] = __builtin_bit_cast(bf16x8, aw);
    }
    __builtin_amdgcn_s_setprio(1);
    // ks2 loads in flight over ks0 MFMAs; ks3 over ks1.
    bf16x8 vC0 = *(const bf16x8*)(vp + 1024);
    bf16x8 vC1 = *(const bf16x8*)(vp + 3072);
    bf16x8 vC2 = *(const bf16x8*)(vp + 5120);
    bf16x8 vC3 = *(const bf16x8*)(vp + 7168);
    oacc[0] = __builtin_amdgcn_mfma_f32_32x32x16_bf16(vA0, pa[0], oacc[0], 0, 0, 0);
    oacc[1] = __builtin_amdgcn_mfma_f32_32x32x16_bf16(vA1, pa[0], oacc[1], 0, 0, 0);
    oacc[2] = __builtin_amdgcn_mfma_f32_32x32x16_bf16(vA2, pa[0], oacc[2], 0, 0, 0);
    oacc[3] = __builtin_amdgcn_mfma_f32_32x32x16_bf16(vA3, pa[0], oacc[3], 0, 0, 0);
    bf16x8 vD0 = *(const bf16x8*)(vp + 1536);
    bf16x8 vD1 = *(const bf16x8*)(vp + 3584);
    bf16x8 vD2 = *(const bf16x8*)(vp + 5632);
    bf16x8 vD3 = *(const bf16x8*)(vp + 7680);
    oacc[0] = __builtin_amdgcn_mfma_f32_32x32x16_bf16(vB0, pa[1], oacc[0], 0, 0, 0);
    oacc[1] = __builtin_amdgcn_mfma_f32_32x32x16_bf16(vB1, pa[1], oacc[1], 0, 0, 0);
    oacc[2] = __builtin_amdgcn_mfma_f32_32x32x16_bf16(vB2, pa[1], oacc[2], 0, 0, 0);
    oacc[3] = __builtin_amdgcn_mfma_f32_32x32x16_bf16(vB3, pa[1], oacc[3], 0, 0, 0);
    oacc[0] = __builtin_amdgcn_mfma_f32_32x32x16_bf16(vC0, pa[2], oacc[0], 0, 0, 0);
    oacc[1] = __builtin_amdgcn_mfma_f32_32x32x16_bf16(vC1, pa[2], oacc[1], 0, 0, 0);
    oacc[2] = __builtin_amdgcn_mfma_f32_32x32x16_bf16(vC2, pa[2], oacc[2], 0, 0, 0);
    oacc[3] = __builtin_amdgcn_mfma_f32_32x32x16_bf16(vC3, pa[2], oacc[3], 0, 0, 0);
    oacc[0] = __builtin_amdgcn_mfma_f32_32x32x16_bf16(vD0, pa[3], oacc[0], 0, 0, 0);
    oacc[1] = __builtin_amdgcn_mfma_f32_32x32x16_bf16(vD1, pa[3], oacc[1], 0, 0, 0);
    oacc[2] = __builtin_amdgcn_mfma_f32_32x32x16_bf16(vD2, pa[3], oacc[2], 0, 0, 0);
    oacc[3] = __builtin_amdgcn_mfma_f32_32x32x16_bf16(vD3, pa[3], oacc[3], 0, 0, 0);
    __builtin_amdgcn_s_setprio(0);

    __syncthreads();   // drains gll16 DMA + K buffer handoff
  }

  const float inv = 1.0f / lrun;
  u16* optr = O + (tokbase + qb*256 + w*32 + l31)*2048 + h*128;
  #pragma unroll
  for (int d = 0; d < 4; ++d){
    #pragma unroll
    for (int t = 0; t < 4; ++t){
      u16x4 ov;
      #pragma unroll
      for (int j = 0; j < 4; ++j) ov[j] = f2bf(oacc[d][4*t + j] * inv);
      *(u16x4*)(optr + d*32 + 8*t + 4*hi) = ov;
    }
  }
}

// ---------------- launch ----------------
extern "C" void kernel_launch(void* const* d_in, const int* in_sizes, int n_in,
                              void* d_out, int out_size, void* d_ws, size_t ws_size,
                              hipStream_t stream)
{
  const float* x    = (const float*)d_in[0];
  const float* qaw  = (const float*)d_in[1];
  const float* qln  = (const float*)d_in[2];
  const float* qbw  = (const float*)d_in[3];
  const float* kvaw = (const float*)d_in[4];
  const float* kvln = (const float*)d_in[5];
  const float* kvbw = (const float*)d_in[6];
  const float* ow   = (const float*)d_in[7];

  char* ws = (char*)d_ws;
  size_t off = 0;
  auto alloc = [&](size_t bytes) -> void* {
    void* p = ws + off;
    off += (bytes + 255) & ~(size_t)255;
    return p;
  };
  u16* xb    = (u16*)alloc(8192UL*2048*2);
  u16* w1    = (u16*)alloc(2304UL*2048*2);
  u16* wqb   = (u16*)alloc(3072UL*1536*2);
  u16* wkvb  = (u16*)alloc(4096UL*512*2);
  u16* wo    = (u16*)alloc(2048UL*2048*2);
  u16* qackv = (u16*)alloc(8192UL*2176*2);
  u16* q     = (u16*)alloc(8192UL*3072*2);
  u16* kn    = (u16*)alloc(8192UL*2048*2);
  u16* vt    = (u16*)alloc(8192UL*2048*2);   // VTf[bh][kt][dblk][slot][lane][8]
  float* tab = (float*)alloc(2048UL*32*2*4);
  u16* ao    = xb;

  k_cvt_all<<<dim3(2048), dim3(256), 0, stream>>>(x, qaw, kvaw, qbw, kvbw, ow,
                                                  xb, w1, wqb, wkvb, wo, tab);
  // q_a + kv_a(c_kv) fused GEMM: M=8192, N=2048, K=2048 -- grid 256 = 1 round
  k_gemm8<0><<<dim3(256), dim3(512), 0, stream>>>(xb, 2048, w1, 2048,
                                                  qackv, 2176, 2048, 2176, 8, nullptr, nullptr);
  // RMS norms + k_pe GEMM tail blocks (merged: saves one dispatch)
  k_normrope<<<dim3(8320), dim3(256), 0, stream>>>(qackv, qln, kvln, xb, w1, tab);
  // fused q_b+RoPE (M=8192,N=3072,K=1536) + kv_b (M=8192,N=4096,K=512)
  k_gemm_qbkvb<<<dim3(896), dim3(512), 0, stream>>>(qackv, wqb, wkvb, q, kn, vt, tab);
  // attention: 512 blocks x 512 threads (8 waves, 256 q-rows)
  k_attn11<<<dim3(512), dim3(512), 0, stream>>>(q, kn, qackv, vt, ao);
  // output projection (fp32 out): M=8192, N=2048, K=2048
  k_gemm8<1><<<dim3(256), dim3(512), 0, stream>>>(ao, 2048, wo, 2048,
                                                  d_out, 2048, 2048, 2048, 8, nullptr, nullptr);
}

// Round 8
// 503.423 us; speedup vs baseline: 1.1087x; 1.1087x over previous
//
#include <hip/hip_runtime.h>
#include <hip/hip_bf16.h>
#include <cstdint>
#include <cstddef>

typedef unsigned short u16;
typedef unsigned int   u32;

typedef __bf16 bf16x8 __attribute__((ext_vector_type(8)));
typedef float  f32x4  __attribute__((ext_vector_type(4)));
typedef float  f32x16 __attribute__((ext_vector_type(16)));
typedef u16    u16x4  __attribute__((ext_vector_type(4)));
typedef u16    u16x8  __attribute__((ext_vector_type(8)));
typedef u32    u32x4  __attribute__((ext_vector_type(4)));

#define DEV static __device__ __forceinline__
#define VMCNT(n) asm volatile("s_waitcnt vmcnt(" #n ")" ::: "memory")
#define LGKM0    asm volatile("s_waitcnt lgkmcnt(0)" ::: "memory")
#define SBARF    do { asm volatile("" ::: "memory"); __builtin_amdgcn_s_barrier(); asm volatile("" ::: "memory"); } while (0)

DEV u16 f2bf(float f){
  union { float f; u32 u; } v; v.f = f;
  u32 r = v.u + 0x7fffu + ((v.u >> 16) & 1u);
  return (u16)(r >> 16);
}
DEV float bf2f(u16 h){
  union { u32 u; float f; } v; v.u = ((u32)h) << 16;
  return v.f;
}
DEV u32 pk2(float a, float b){
  __hip_bfloat16 x = __float2bfloat16(a), y = __float2bfloat16(b);
  return (u32)__builtin_bit_cast(u16, x) | ((u32)__builtin_bit_cast(u16, y) << 16);
}
DEV float fexp2(float x){ float r; asm("v_exp_f32 %0, %1" : "=v"(r) : "v"(x)); return r; }
DEV float mx3(float a, float b, float c){ return fmaxf(fmaxf(a, b), c); }
DEV float tree16(const f32x16& p){
  float a = mx3(p[0],p[1],p[2]),  b = mx3(p[3],p[4],p[5]);
  float c = mx3(p[6],p[7],p[8]),  d = mx3(p[9],p[10],p[11]);
  float e = mx3(p[12],p[13],p[14]);
  return fmaxf(mx3(a,b,c), mx3(d,e,p[15]));
}
DEV void gll16(const void* g, void* l){
  __builtin_amdgcn_global_load_lds(
      (const __attribute__((address_space(1))) u32*)g,
      (__attribute__((address_space(3))) u32*)l, 16, 0, 0);
}

// ---------------- fused converts + RoPE table ----------------
// w1 layout: rows 0..1536 = q_a_w; 1536..2048 = kv_a_w (c_kv part);
// 2048..2112 = kv_a_w k_pe rows ROPE-PERMUTED (even dims at j<32, odd at
// j>=32, matching the q_pe weight permutation) -- consumed by k_kpe.
__global__ void k_cvt_all(const float* __restrict__ x,  const float* __restrict__ qaw,
                          const float* __restrict__ kvaw, const float* __restrict__ qbw,
                          const float* __restrict__ kvbw, const float* __restrict__ ow,
                          u16* __restrict__ xb, u16* __restrict__ w1, u16* __restrict__ wqb,
                          u16* __restrict__ wkvb, u16* __restrict__ wo,
                          float* __restrict__ tab){
  const long stride = (long)gridDim.x * blockDim.x;
  for (long i = (long)blockIdx.x * blockDim.x + threadIdx.x; i < 8192000L; i += stride){
    if (i >= 8126464L){
      int idx = (int)(i - 8126464L);          // 65536 entries
      int s = idx >> 5, p = idx & 31;
      float freq = exp2f(-(float)p * 0.41524101186f);   // log2(10000)/32
      float ang = (float)s * freq;
      tab[idx*2]   = cosf(ang);
      tab[idx*2+1] = sinf(ang);
      continue;
    }
    const float* src; u16* dst;
    if (i < 4194304L){ long e = i*4; src = x + e; dst = xb + e; }
    else if (i < 5373952L){
      long e = (i - 4194304L) * 4;
      int row = (int)(e >> 11), col = (int)(e & 2047);
      dst = w1 + e;
      if (row < 1536) src = qaw + (long)row*2048 + col;
      else if (row < 2048) src = kvaw + (long)(row-1536)*2048 + col;
      else if (row < 2112){
        int j = row - 2048;
        int sj = (j < 32) ? (2*j) : (2*(j-32)+1);      // rope-permute k_pe rows
        src = kvaw + (long)(512 + sj)*2048 + col;
      }
      else { u16x4 z; z[0]=0;z[1]=0;z[2]=0;z[3]=0; *(u16x4*)dst = z; continue; }
    }
    else if (i < 6553600L){
      long e = (i - 5373952L)*4;
      int row = (int)(e / 1536), col = (int)(e - (long)row*1536);
      int dd = row % 192;
      int srow = row;
      if (dd >= 128){
        int j = dd - 128;
        int sdd = (j < 32) ? (128 + 2*j) : (128 + 2*(j - 32) + 1);
        srow = row - dd + sdd;
      }
      src = qbw + (long)srow*1536 + col; dst = wqb + e;
    }
    else if (i < 7077888L){ long e = (i - 6553600L)*4; src = kvbw + e; dst = wkvb + e; }
    else { long e = (i - 7077888L)*4; src = ow + e; dst = wo + e; }
    f32x4 f = *(const f32x4*)src;
    u16x4 o4;
    o4[0]=f2bf(f[0]); o4[1]=f2bf(f[1]); o4[2]=f2bf(f[2]); o4[3]=f2bf(f[3]);
    *(u16x4*)dst = o4;
  }
}

// ---------------- 256x256 8-wave 4-phase GEMM body ----------------
// CMODE: 0 = bf16 store (masked at Nlim), 1 = f32 store,
//        2 = kv-split (k_nope rowmajor + V fragment-major VTf layout:
//            [bh][kt][dblk][slot][lane][8], slot = sigma(kk)>>3, so the attn
//            PV A-fragment is one coalesced 16B/lane wave load),
//        3 = bf16 store with fused q_pe RoPE (table-based, rope-permuted weights)
template<int CMODE>
DEV void gemm_body(u16 (*sm)[32768], int bm, int bn,
                   const u16* __restrict__ A, int lda,
                   const u16* __restrict__ B, int ldb,
                   void* __restrict__ Cp, int ldc, int K, int Nlim,
                   u16* __restrict__ kn, u16* __restrict__ vt,
                   const float* __restrict__ tab)
{
  const int tid = threadIdx.x;
  const int l   = tid & 63;
  const int wv  = tid >> 6;
  const int wr  = wv >> 2, wc = wv & 3;
  const int l15 = l & 15, l4 = l >> 4;
  const long M0 = (long)bm * 256, N0 = (long)bn * 256;

  const int c7 = tid & 7;
  const u16* asrc[4]; const u16* bsrc[4];
  int dsta[4], dstb[4];
  #pragma unroll
  for (int s = 0; s < 4; ++s){
    int slot = s*512 + tid;
    int row  = slot >> 3;
    asrc[s] = A + (M0 + row)*lda + ((c7 ^ (row & 7)) << 3);
    bsrc[s] = B + (N0 + row)*ldb + ((c7 ^ (row & 7)) << 3);
    dsta[s] = slot*8;
    dstb[s] = 16384 + slot*8;
  }
  auto stA = [&](int s, int kt, int nb){ gll16(asrc[s] + (long)kt*64, &sm[nb][dsta[s]]); };
  auto stB = [&](int s, int kt, int nb){ gll16(bsrc[s] + (long)kt*64, &sm[nb][dstb[s]]); };

  auto rdA = [&](int buf, int m, int ks) -> bf16x8 {
    int row = wr*128 + m*16 + l15;
    int ch  = ks*4 + l4;
    return *(const bf16x8*)&sm[buf][row*64 + ((ch ^ (row & 7)) << 3)];
  };
  auto rdB = [&](int buf, int n, int ks) -> bf16x8 {
    int row = wc*64 + n*16 + l15;
    int ch  = ks*4 + l4;
    return *(const bf16x8*)&sm[buf][16384 + row*64 + ((ch ^ (row & 7)) << 3)];
  };

  f32x4 acc[8][4];
  #pragma unroll
  for (int m = 0; m < 8; ++m)
    #pragma unroll
    for (int n = 0; n < 4; ++n)
      acc[m][n] = (f32x4)0.0f;

  stB(0,0,0); stB(2,0,0); stB(1,0,0); stB(3,0,0);
  stA(0,0,0); stA(2,0,0); stA(1,0,0); stA(3,0,0);
  VMCNT(2);
  SBARF;

  const int NT = K >> 6;
  for (int t = 0; t < NT; ++t){
    const int cb = t & 1, nb = cb ^ 1;
    const bool PF = (t + 1 < NT);
    bf16x8 bfr[4][2];
    #pragma unroll
    for (int p = 0; p < 4; ++p){
      bf16x8 af[2][2];
      #pragma unroll
      for (int mm = 0; mm < 2; ++mm)
        #pragma unroll
        for (int ks = 0; ks < 2; ++ks)
          af[mm][ks] = rdA(cb, p*2 + mm, ks);
      if (p == 0){
        #pragma unroll
        for (int n = 0; n < 4; ++n)
          #pragma unroll
          for (int ks = 0; ks < 2; ++ks)
            bfr[n][ks] = rdB(cb, n, ks);
        if (PF){ stB(0, t+1, nb); stB(2, t+1, nb); }
      } else if (p == 1){
        if (PF){ stB(1, t+1, nb); stB(3, t+1, nb); }
      } else if (p == 2){
        if (PF){ stA(0, t+1, nb); stA(2, t+1, nb); }
      } else {
        if (PF){ stA(1, t+1, nb); stA(3, t+1, nb); }
      }
      SBARF;
      LGKM0;
      __builtin_amdgcn_s_setprio(1);
      #pragma unroll
      for (int mm = 0; mm < 2; ++mm)
        #pragma unroll
        for (int n = 0; n < 4; ++n)
          #pragma unroll
          for (int ks = 0; ks < 2; ++ks)
            acc[p*2+mm][n] = __builtin_amdgcn_mfma_f32_16x16x32_bf16(af[mm][ks], bfr[n][ks], acc[p*2+mm][n], 0, 0, 0);
      __builtin_amdgcn_s_setprio(0);
      if (p == 1){ if (PF) VMCNT(4); else VMCNT(0); }
      if (p == 3 && PF) VMCNT(2);
      SBARF;
    }
  }

  const long rbase = M0 + wr*128 + l4*4;
  const long cbase = N0 + wc*64 + l15;

  if (CMODE == 3){
    const bool ropeblk = (((N0 + wc*64) % 192) == 128);
    if (ropeblk){
      #pragma unroll
      for (int n = 0; n < 2; ++n){
        const int p = l15 + 16*n;
        #pragma unroll
        for (int m = 0; m < 8; ++m){
          #pragma unroll
          for (int i = 0; i < 4; ++i){
            long r = rbase + m*16 + i;
            const float* cs2 = tab + (((int)(r & 2047))*32 + p)*2;
            float cs = cs2[0], sn = cs2[1];
            float e = acc[m][n][i], o = acc[m][n+2][i];
            ((u16*)Cp)[r * ldc + cbase + n*16]       = f2bf(e*cs - o*sn);
            ((u16*)Cp)[r * ldc + cbase + (n+2)*16]   = f2bf(o*cs + e*sn);
          }
        }
      }
    } else {
      #pragma unroll
      for (int m = 0; m < 8; ++m)
        #pragma unroll
        for (int n = 0; n < 4; ++n)
          #pragma unroll
          for (int i = 0; i < 4; ++i)
            ((u16*)Cp)[(rbase + m*16 + i) * ldc + cbase + n*16] = f2bf(acc[m][n][i]);
    }
    return;
  }

  #pragma unroll
  for (int m = 0; m < 8; ++m){
    #pragma unroll
    for (int n = 0; n < 4; ++n){
      const long c  = cbase + n*16;
      const long r0 = rbase + m*16;
      if (CMODE == 0){
        if (c < Nlim){
          #pragma unroll
          for (int i = 0; i < 4; ++i)
            ((u16*)Cp)[(r0 + i) * ldc + c] = f2bf(acc[m][n][i]);
        }
      } else if (CMODE == 1){
        #pragma unroll
        for (int i = 0; i < 4; ++i)
          ((float*)Cp)[(r0 + i) * ldc + c] = acc[m][n][i];
      } else {
        int h = (int)(c >> 8), rem = (int)(c & 255);
        if (rem < 128){
          #pragma unroll
          for (int i = 0; i < 4; ++i)
            kn[(r0 + i) * 2048 + h*128 + rem] = f2bf(acc[m][n][i]);
        } else {
          // V fragment-major: VTf[bh][kt][dblk][slot][lane][8]
          //   token s -> kt = s>>6, kk = s&63, kkp = sigma(kk) (swap 4-blocks
          //   1<->2 within 16); slot = kkp>>3, e = kkp&7.
          // r0%4==0 and sigma preserves 4-runs -> u16x4 store stays contiguous.
          int bb = (int)(r0 >> 11), s = (int)(r0 & 2047);
          int kk = s & 63;
          int kkp = (kk & ~12) | ((kk & 4) << 1) | ((kk & 8) >> 1);
          int kt = s >> 6;
          int dfull = rem - 128;
          int bh = bb*16 + h;
          long idx = ((((long)bh*32 + kt)*4 + (dfull>>5))*8 + (kkp>>3))*256
                   + (dfull & 31)*8 + (kkp & 7);
          u16x4 pv;
          #pragma unroll
          for (int i = 0; i < 4; ++i) pv[i] = f2bf(acc[m][n][i]);
          *(u16x4*)&vt[idx] = pv;
        }
      }
    }
  }
}

template<int CMODE>
__global__ __launch_bounds__(512, 1)
void k_gemm8(const u16* __restrict__ A, int lda,
             const u16* __restrict__ B, int ldb,
             void* __restrict__ Cp, int ldc, int K, int Nlim, int gy,
             u16* __restrict__ kn, u16* __restrict__ vt)
{
  __shared__ u16 sm[2][32768];
  const int flat = blockIdx.x;
  const int id2  = (flat & 7) * ((int)gridDim.x >> 3) + (flat >> 3);
  gemm_body<CMODE>(sm, id2 / gy, id2 % gy, A, lda, B, ldb, Cp, ldc, K, Nlim, kn, vt, nullptr);
}

// fused q_b (+RoPE via table) + kv_b: grid 896; per XCD: 48 q_b + 64 kv_b blocks
__global__ __launch_bounds__(512, 1)
void k_gemm_qbkvb(const u16* __restrict__ qackv, const u16* __restrict__ wqb,
                  const u16* __restrict__ wkvb, u16* __restrict__ q,
                  u16* __restrict__ kn, u16* __restrict__ vt,
                  const float* __restrict__ tab)
{
  __shared__ u16 sm[2][32768];
  const int flat = blockIdx.x;
  const int grp = flat >> 3, sub = flat & 7;
  if (grp < 48){
    int i = sub*48 + grp;
    gemm_body<3>(sm, i/12, i%12, qackv, 2176, wqb, 1536, q, 3072, 1536, 3072, nullptr, nullptr, tab);
  } else {
    int i = sub*64 + (grp - 48);
    gemm_body<2>(sm, i/16, i%16, qackv + 1536, 2176, wkvb, 512, nullptr, 0, 512, 4096, kn, vt, nullptr);
  }
}

// ---------------- k_pe GEMM (M=8192, N=64, K=2048) + fused RoPE ----------------
// 512 one-wave blocks, 16 rows each; register-only MFMA, A/B direct from
// global (B panel = 64 rows of w1, 256KB, L2-resident). Weights are
// rope-permuted by cvt, so rope pairs are (n, n+2) fragments of one lane.
// Output: roped k_pe -> qackv cols 2048..2112 (fp32 rope, then bf16).
// NOTE (rounds 6/7): folding this into qbkvb or normrope regresses 30-54us
// (co-compilation/regalloc perturbation, rule #19). Keep standalone.
__global__ __launch_bounds__(64)
void k_kpe(const u16* __restrict__ xb, const u16* __restrict__ w1,
           u16* __restrict__ qackv, const float* __restrict__ tab)
{
  const int l = threadIdx.x;
  const int l15 = l & 15, l4 = l >> 4;
  const long M0 = (long)blockIdx.x * 16;

  f32x4 acc[4];
  #pragma unroll
  for (int n = 0; n < 4; ++n) acc[n] = (f32x4)0.0f;

  const u16* aptr = xb + (M0 + l15)*2048 + l4*8;
  const u16* bptr = w1 + (2048 + l15)*2048 + l4*8;

  #pragma unroll 2
  for (int kt = 0; kt < 32; ++kt){
    bf16x8 a[2], b[4][2];
    #pragma unroll
    for (int ks = 0; ks < 2; ++ks)
      a[ks] = *(const bf16x8*)(aptr + kt*64 + ks*32);
    #pragma unroll
    for (int n = 0; n < 4; ++n)
      #pragma unroll
      for (int ks = 0; ks < 2; ++ks)
        b[n][ks] = *(const bf16x8*)(bptr + (long)n*16*2048 + kt*64 + ks*32);
    #pragma unroll
    for (int n = 0; n < 4; ++n)
      #pragma unroll
      for (int ks = 0; ks < 2; ++ks)
        acc[n] = __builtin_amdgcn_mfma_f32_16x16x32_bf16(a[ks], b[n][ks], acc[n], 0, 0, 0);
  }

  // cols: c = n*16 + l15 in rope-permuted space (even part c<32, odd c>=32)
  #pragma unroll
  for (int n = 0; n < 2; ++n){
    const int p = l15 + 16*n;
    #pragma unroll
    for (int i = 0; i < 4; ++i){
      long r = M0 + l4*4 + i;
      const float* cs2 = tab + (((int)(r & 2047))*32 + p)*2;
      float cs = cs2[0], sn = cs2[1];
      float e = acc[n][i], o = acc[n+2][i];
      qackv[r*2176 + 2048 + p]      = f2bf(e*cs - o*sn);
      qackv[r*2176 + 2048 + 32 + p] = f2bf(o*cs + e*sn);
    }
  }
}

// ---------------- RMS norms (in place; k_pe handled by k_kpe) ----------------
__global__ __launch_bounds__(256)
void k_normrope(u16* __restrict__ qackv, const float* __restrict__ qln,
                const float* __restrict__ kvln){
  const int tok = blockIdx.x;
  const int tid = threadIdx.x;
  u16* row = qackv + (long)tok * 2176;
  __shared__ float red[8];

  float v[6]; float ss = 0.f;
  #pragma unroll
  for (int i = 0; i < 6; ++i){
    int c = tid + i*256;
    v[i] = bf2f(row[c]);
    ss += v[i]*v[i];
  }
  #pragma unroll
  for (int m = 32; m >= 1; m >>= 1) ss += __shfl_xor(ss, m);
  if ((tid & 63) == 0) red[tid >> 6] = ss;
  __syncthreads();
  float tot = red[0] + red[1] + red[2] + red[3];
  float r1 = rsqrtf(tot * (1.0f/1536.0f) + 1e-6f);
  #pragma unroll
  for (int i = 0; i < 6; ++i){
    int c = tid + i*256;
    row[c] = f2bf(v[i] * r1 * qln[c]);
  }

  float u0 = bf2f(row[1536 + tid]);
  float u1 = bf2f(row[1536 + 256 + tid]);
  float s2 = u0*u0 + u1*u1;
  #pragma unroll
  for (int m = 32; m >= 1; m >>= 1) s2 += __shfl_xor(s2, m);
  if ((tid & 63) == 0) red[4 + (tid >> 6)] = s2;
  __syncthreads();
  float tot2 = red[4] + red[5] + red[6] + red[7];
  float r2 = rsqrtf(tot2 * (1.0f/512.0f) + 1e-6f);
  row[1536 + tid]       = f2bf(u0 * r2 * kvln[tid]);
  row[1536 + 256 + tid] = f2bf(u1 * r2 * kvln[256 + tid]);
}

// ---------------- attention v13 (round-2 best): K in LDS (dbuf, 48KB);
// V fragment-major direct from global (coalesced 16B/lane, L1-resident:
// all 8 waves read the same 16KB tile). V loads pipelined: ks0/ks1 issued
// before softmax (latency hidden under VALU), ks2/ks3 between PV MFMA groups.
__global__ __launch_bounds__(512)
void k_attn11(const u16* __restrict__ Q, const u16* __restrict__ KN,
              const u16* __restrict__ CKV, const u16* __restrict__ VT,
              u16* __restrict__ O)
{
  __shared__ u16 sK[2][64*192];   // row stride 384B, XOR-swizzled content

  const int tid = threadIdx.x;
  const int l   = tid & 63;
  const int w   = tid >> 6;
  const int l31 = l & 31;
  const int hi  = l >> 5;
  const int swz = l31 & 7;
  const int flat = blockIdx.x;
  const int qb  = flat >> 6;
  const int bh  = ((flat & 7) << 3) | ((flat >> 3) & 7);
  const int b   = bh >> 4, h = bh & 15;
  const long tokbase = (long)b << 11;

  bf16x8 qf[12];
  {
    const u16* qptr = Q + (tokbase + qb*256 + w*32 + l31)*3072 + h*192 + hi*8;
    #pragma unroll
    for (int s = 0; s < 12; ++s)
      qf[s] = *(const bf16x8*)(qptr + s*16);
  }

  const u16* ksrc[3]; int kstep[3]; int kdst[3];
  #pragma unroll
  for (int i = 0; i < 3; ++i){
    int ch = tid + i*512;
    int row = ch / 24;
    int cc  = ch - row*24;
    int sc  = cc ^ (row & 7);
    if (sc < 16){ ksrc[i] = KN  + (tokbase + row)*2048 + h*128 + sc*8;       kstep[i] = 64*2048; }
    else        { ksrc[i] = CKV + (tokbase + row)*2176 + 2048 + (sc-16)*8;   kstep[i] = 64*2176; }
    kdst[i] = ch*8;
  }
  auto STAGE = [&](int kt, int nb){
    #pragma unroll
    for (int i = 0; i < 3; ++i) gll16(ksrc[i] + (long)kt*kstep[i], &sK[nb][kdst[i]]);
  };

  // V fragment base: VTf[bh][kt][dblk][slot][lane][8]; per-lane offset
  // hi*256 + l31*8 elems -> one wave load = contiguous 1KB.
  const u16* vbase = VT + (long)bh*(32*8192) + hi*256 + l31*8;

  f32x16 oacc[4];
  #pragma unroll
  for (int i = 0; i < 4; ++i) oacc[i] = (f32x16)0.0f;
  float mrun = -1e30f, lrun = 0.f;
  const float scale2 = (float)(0.07216878364870323 * 1.4426950408889634);  // 192^-0.5 * log2e

  STAGE(0, 0);
  __syncthreads();

  for (int kt = 0; kt < 32; ++kt){
    const int cur = kt & 1;
    if (kt < 31) STAGE(kt + 1, cur ^ 1);

    const char* kb = (const char*)&sK[cur][0];
    const u16*  vp = vbase + (long)kt*8192;

    f32x16 p0 = (f32x16)0.0f, p1 = (f32x16)0.0f;
    __builtin_amdgcn_s_setprio(1);
    #pragma unroll
    for (int s = 0; s < 12; ++s){
      const int co = ((2*s + hi) ^ swz) << 4;
      bf16x8 k0 = *(const bf16x8*)(kb + l31*384 + co);
      bf16x8 k1 = *(const bf16x8*)(kb + (32 + l31)*384 + co);
      p0 = __builtin_amdgcn_mfma_f32_32x32x16_bf16(k0, qf[s], p0, 0, 0, 0);
      p1 = __builtin_amdgcn_mfma_f32_32x32x16_bf16(k1, qf[s], p1, 0, 0, 0);
    }
    __builtin_amdgcn_s_setprio(0);

    // issue ks0/ks1 V fragments now -> latency hides under softmax VALU
    bf16x8 vA0 = *(const bf16x8*)(vp + 0);
    bf16x8 vA1 = *(const bf16x8*)(vp + 2048);
    bf16x8 vA2 = *(const bf16x8*)(vp + 4096);
    bf16x8 vA3 = *(const bf16x8*)(vp + 6144);
    bf16x8 vB0 = *(const bf16x8*)(vp + 512);
    bf16x8 vB1 = *(const bf16x8*)(vp + 2560);
    bf16x8 vB2 = *(const bf16x8*)(vp + 4608);
    bf16x8 vB3 = *(const bf16x8*)(vp + 6656);

    float rm = fmaxf(tree16(p0), tree16(p1));
    rm = fmaxf(rm, __shfl_xor(rm, 32));
    const float om = rm * scale2;
    if (!__all(om <= mrun + 8.0f)){          // defer-max (T13)
      float mn = fmaxf(mrun, om);
      float corr = fexp2(mrun - mn);
      mrun = mn;
      lrun *= corr;
      #pragma unroll
      for (int d = 0; d < 4; ++d)
        #pragma unroll
        for (int r = 0; r < 16; ++r) oacc[d][r] *= corr;
    }
    float ls = 0.f;
    #pragma unroll
    for (int r = 0; r < 16; ++r){ p0[r] = fexp2(__builtin_fmaf(p0[r], scale2, -mrun)); ls += p0[r]; }
    #pragma unroll
    for (int r = 0; r < 16; ++r){ p1[r] = fexp2(__builtin_fmaf(p1[r], scale2, -mrun)); ls += p1[r]; }
    lrun += ls + __shfl_xor(ls, 32);

    // PV: shuffle-free fragments (sigma k-permutation baked into VTf).
    bf16x8 pa[4];
    #pragma unroll
    for (int ks = 0; ks < 4; ++ks){
      const f32x16 ps = (ks < 2) ? p0 : p1;
      const int rb = (ks & 1) * 8;
      u32x4 aw;
      aw[0] = pk2(ps[rb+0], ps[rb+1]);
      aw[1] = pk2(ps[rb+2], ps[rb+3]);
      aw[2] = pk2(ps[rb+4], ps[rb+5]);
      aw[3] = pk2(ps[rb+6], ps[rb+7]);
      pa[ks] = __builtin_bit_cast(bf16x8, aw);
    }
    __builtin_amdgcn_s_setprio(1);
    // ks2 loads in flight over ks0 MFMAs; ks3 over ks1.
    bf16x8 vC0 = *(const bf16x8*)(vp + 1024);
    bf16x8 vC1 = *(const bf16x8*)(vp + 3072);
    bf16x8 vC2 = *(const bf16x8*)(vp + 5120);
    bf16x8 vC3 = *(const bf16x8*)(vp + 7168);
    oacc[0] = __builtin_amdgcn_mfma_f32_32x32x16_bf16(vA0, pa[0], oacc[0], 0, 0, 0);
    oacc[1] = __builtin_amdgcn_mfma_f32_32x32x16_bf16(vA1, pa[0], oacc[1], 0, 0, 0);
    oacc[2] = __builtin_amdgcn_mfma_f32_32x32x16_bf16(vA2, pa[0], oacc[2], 0, 0, 0);
    oacc[3] = __builtin_amdgcn_mfma_f32_32x32x16_bf16(vA3, pa[0], oacc[3], 0, 0, 0);
    bf16x8 vD0 = *(const bf16x8*)(vp + 1536);
    bf16x8 vD1 = *(const bf16x8*)(vp + 3584);
    bf16x8 vD2 = *(const bf16x8*)(vp + 5632);
    bf16x8 vD3 = *(const bf16x8*)(vp + 7680);
    oacc[0] = __builtin_amdgcn_mfma_f32_32x32x16_bf16(vB0, pa[1], oacc[0], 0, 0, 0);
    oacc[1] = __builtin_amdgcn_mfma_f32_32x32x16_bf16(vB1, pa[1], oacc[1], 0, 0, 0);
    oacc[2] = __builtin_amdgcn_mfma_f32_32x32x16_bf16(vB2, pa[1], oacc[2], 0, 0, 0);
    oacc[3] = __builtin_amdgcn_mfma_f32_32x32x16_bf16(vB3, pa[1], oacc[3], 0, 0, 0);
    oacc[0] = __builtin_amdgcn_mfma_f32_32x32x16_bf16(vC0, pa[2], oacc[0], 0, 0, 0);
    oacc[1] = __builtin_amdgcn_mfma_f32_32x32x16_bf16(vC1, pa[2], oacc[1], 0, 0, 0);
    oacc[2] = __builtin_amdgcn_mfma_f32_32x32x16_bf16(vC2, pa[2], oacc[2], 0, 0, 0);
    oacc[3] = __builtin_amdgcn_mfma_f32_32x32x16_bf16(vC3, pa[2], oacc[3], 0, 0, 0);
    oacc[0] = __builtin_amdgcn_mfma_f32_32x32x16_bf16(vD0, pa[3], oacc[0], 0, 0, 0);
    oacc[1] = __builtin_amdgcn_mfma_f32_32x32x16_bf16(vD1, pa[3], oacc[1], 0, 0, 0);
    oacc[2] = __builtin_amdgcn_mfma_f32_32x32x16_bf16(vD2, pa[3], oacc[2], 0, 0, 0);
    oacc[3] = __builtin_amdgcn_mfma_f32_32x32x16_bf16(vD3, pa[3], oacc[3], 0, 0, 0);
    __builtin_amdgcn_s_setprio(0);

    __syncthreads();   // drains gll16 DMA + K buffer handoff
  }

  const float inv = 1.0f / lrun;
  u16* optr = O + (tokbase + qb*256 + w*32 + l31)*2048 + h*128;
  #pragma unroll
  for (int d = 0; d < 4; ++d){
    #pragma unroll
    for (int t = 0; t < 4; ++t){
      u16x4 ov;
      #pragma unroll
      for (int j = 0; j < 4; ++j) ov[j] = f2bf(oacc[d][4*t + j] * inv);
      *(u16x4*)(optr + d*32 + 8*t + 4*hi) = ov;
    }
  }
}

// ---------------- launch ----------------
extern "C" void kernel_launch(void* const* d_in, const int* in_sizes, int n_in,
                              void* d_out, int out_size, void* d_ws, size_t ws_size,
                              hipStream_t stream)
{
  const float* x    = (const float*)d_in[0];
  const float* qaw  = (const float*)d_in[1];
  const float* qln  = (const float*)d_in[2];
  const float* qbw  = (const float*)d_in[3];
  const float* kvaw = (const float*)d_in[4];
  const float* kvln = (const float*)d_in[5];
  const float* kvbw = (const float*)d_in[6];
  const float* ow   = (const float*)d_in[7];

  char* ws = (char*)d_ws;
  size_t off = 0;
  auto alloc = [&](size_t bytes) -> void* {
    void* p = ws + off;
    off += (bytes + 255) & ~(size_t)255;
    return p;
  };
  u16* xb    = (u16*)alloc(8192UL*2048*2);
  u16* w1    = (u16*)alloc(2304UL*2048*2);
  u16* wqb   = (u16*)alloc(3072UL*1536*2);
  u16* wkvb  = (u16*)alloc(4096UL*512*2);
  u16* wo    = (u16*)alloc(2048UL*2048*2);
  u16* qackv = (u16*)alloc(8192UL*2176*2);
  u16* q     = (u16*)alloc(8192UL*3072*2);
  u16* kn    = (u16*)alloc(8192UL*2048*2);
  u16* vt    = (u16*)alloc(8192UL*2048*2);   // VTf[bh][kt][dblk][slot][lane][8]
  float* tab = (float*)alloc(2048UL*32*2*4);
  u16* ao    = xb;

  k_cvt_all<<<dim3(2048), dim3(256), 0, stream>>>(x, qaw, kvaw, qbw, kvbw, ow,
                                                  xb, w1, wqb, wkvb, wo, tab);
  // q_a + kv_a(c_kv) fused GEMM: M=8192, N=2048, K=2048 -- grid 256 = 1 round
  k_gemm8<0><<<dim3(256), dim3(512), 0, stream>>>(xb, 2048, w1, 2048,
                                                  qackv, 2176, 2048, 2176, 8, nullptr, nullptr);
  // k_pe GEMM + fused RoPE (M=8192, N=64, K=2048)
  k_kpe<<<dim3(512), dim3(64), 0, stream>>>(xb, w1, qackv, tab);
  k_normrope<<<dim3(8192), dim3(256), 0, stream>>>(qackv, qln, kvln);
  // fused q_b+RoPE (M=8192,N=3072,K=1536) + kv_b (M=8192,N=4096,K=512)
  k_gemm_qbkvb<<<dim3(896), dim3(512), 0, stream>>>(qackv, wqb, wkvb, q, kn, vt, tab);
  // attention: 512 blocks x 512 threads (8 waves, 256 q-rows)
  k_attn11<<<dim3(512), dim3(512), 0, stream>>>(q, kn, qackv, vt, ao);
  // output projection (fp32 out): M=8192, N=2048, K=2048
  k_gemm8<1><<<dim3(256), dim3(512), 0, stream>>>(ao, 2048, wo, 2048,
                                                  d_out, 2048, 2048, 2048, 8, nullptr, nullptr);
}